// Round 1
// baseline (4093.450 us; speedup 1.0000x reference)
//
#include <hip/hip_runtime.h>
#include <math.h>

#define NNODES 50000
#define NEDGES 400000
#define HEADS 4

// ---------------- GEMM: Y[n,m] = X[n,k] @ W[k,m], fp32, 16x16 tiles ----------
__global__ void gemm_tiled(const float* __restrict__ X, const float* __restrict__ W,
                           float* __restrict__ Y, int n, int k, int m) {
    __shared__ float sX[16][17];
    __shared__ float sW[16][17];
    int tx = threadIdx.x, ty = threadIdx.y;
    int row = blockIdx.y * 16 + ty;
    int col = blockIdx.x * 16 + tx;
    float acc = 0.f;
    for (int k0 = 0; k0 < k; k0 += 16) {
        int kx = k0 + tx, ky = k0 + ty;
        sX[ty][tx] = (row < n && kx < k) ? X[(size_t)row * k + kx] : 0.f;
        sW[ty][tx] = (ky < k && col < m) ? W[(size_t)ky * m + col] : 0.f;
        __syncthreads();
#pragma unroll
        for (int kk = 0; kk < 16; ++kk) acc += sX[ty][kk] * sW[kk][tx];
        __syncthreads();
    }
    if (row < n && col < m) Y[(size_t)row * m + col] = acc;
}

// -------------- per-(node,head) attention scalars ----------------------------
__global__ void att_scalar(const float* __restrict__ Wx, const float* __restrict__ a,
                           float* __restrict__ asrc, float* __restrict__ adst,
                           int hd, int dout) {
    int idx = blockIdx.x * blockDim.x + threadIdx.x;
    if (idx >= NNODES * HEADS) return;
    int node = idx >> 2, h = idx & 3;
    const float* base = Wx + (size_t)node * dout + h * hd;
    float s1 = 0.f, s2 = 0.f;
    for (int d = 0; d < hd; ++d) {
        float v = base[d];
        s1 += v * a[d];
        s2 += v * a[hd + d];
    }
    asrc[idx] = s1;
    adst[idx] = s2;
}

// -------------- per-(edge,head) logits: leaky-relu, exp, denom accumulation --
__global__ void edge_logits(const int* __restrict__ src, const int* __restrict__ dst,
                            const float* __restrict__ asrc, const float* __restrict__ adst,
                            float* __restrict__ eexp, float* __restrict__ den) {
    int idx = blockIdx.x * blockDim.x + threadIdx.x;
    if (idx >= NEDGES * HEADS) return;
    int e = idx >> 2, h = idx & 3;
    int s = src[e], d = dst[e];
    float x = asrc[s * HEADS + h] + adst[d * HEADS + h];
    x = x > 0.f ? x : 0.2f * x;
    float ex = expf(x);
    eexp[idx] = ex;
    atomicAdd(&den[d * HEADS + h], ex);
}

// -------------- per-(edge,feature) weighted scatter --------------------------
__global__ void scatter_acc(const int* __restrict__ src, const int* __restrict__ dst,
                            const float* __restrict__ eexp, const float* __restrict__ den,
                            const float* __restrict__ Wx, float* __restrict__ acc,
                            int dout_shift, int hd_shift) {
    unsigned idx = blockIdx.x * blockDim.x + threadIdx.x;
    unsigned total = (unsigned)NEDGES << dout_shift;
    if (idx >= total) return;
    unsigned e = idx >> dout_shift;
    unsigned j = idx & ((1u << dout_shift) - 1u);
    unsigned h = j >> hd_shift;
    int s = src[e], d = dst[e];
    float w = eexp[e * HEADS + h] / (den[d * HEADS + h] + 1e-8f);
    atomicAdd(&acc[((size_t)d << dout_shift) + j], w * Wx[((size_t)s << dout_shift) + j]);
}

// -------------- ELU + LayerNorm, one block (256 thr) per node ----------------
__global__ void elu_ln(const float* __restrict__ acc, const float* __restrict__ g,
                       const float* __restrict__ b, float* __restrict__ out, int dout) {
    int node = blockIdx.x;
    int tid = threadIdx.x;
    const float* row = acc + (size_t)node * dout;
    int per = dout >> 8;  // 1 or 2
    float vals[2];
    float lsum = 0.f, lsq = 0.f;
    for (int i = 0; i < per; ++i) {
        float v = row[i * 256 + tid];
        v = v > 0.f ? v : expm1f(v);
        vals[i] = v;
        lsum += v;
        lsq += v * v;
    }
    // wave (64-lane) reduction
    for (int off = 32; off; off >>= 1) {
        lsum += __shfl_down(lsum, off);
        lsq += __shfl_down(lsq, off);
    }
    __shared__ float ssum[4], ssq[4];
    __shared__ float smean, srstd;
    int wid = tid >> 6, lane = tid & 63;
    if (lane == 0) { ssum[wid] = lsum; ssq[wid] = lsq; }
    __syncthreads();
    if (tid == 0) {
        float ts = ssum[0] + ssum[1] + ssum[2] + ssum[3];
        float tq = ssq[0] + ssq[1] + ssq[2] + ssq[3];
        float mean = ts / dout;
        float var = tq / dout - mean * mean;
        smean = mean;
        srstd = rsqrtf(var + 1e-5f);
    }
    __syncthreads();
    float mean = smean, rstd = srstd;
    for (int i = 0; i < per; ++i) {
        int j = i * 256 + tid;
        out[(size_t)node * dout + j] = (vals[i] - mean) * rstd * g[j] + b[j];
    }
}

extern "C" void kernel_launch(void* const* d_in, const int* in_sizes, int n_in,
                              void* d_out, int out_size, void* d_ws, size_t ws_size,
                              hipStream_t stream) {
    const float* x0 = (const float*)d_in[0];
    const int* ei = (const int*)d_in[1];
    const int* src = ei;             // edge_index[0]
    const int* dst = ei + NEDGES;    // edge_index[1]
    const float* W[3]  = {(const float*)d_in[2], (const float*)d_in[6],  (const float*)d_in[10]};
    const float* a[3]  = {(const float*)d_in[3], (const float*)d_in[7],  (const float*)d_in[11]};
    const float* g[3]  = {(const float*)d_in[4], (const float*)d_in[8],  (const float*)d_in[12]};
    const float* bb[3] = {(const float*)d_in[5], (const float*)d_in[9],  (const float*)d_in[13]};

    // workspace layout (floats)
    float* A    = (float*)d_ws;                       // N*512  ping buffer (layer outputs 1,2)
    float* Wx   = A    + (size_t)NNODES * 512;        // N*512
    float* ACC  = Wx   + (size_t)NNODES * 512;        // N*512
    float* EEXP = ACC  + (size_t)NNODES * 512;        // E*HEADS
    float* DEN  = EEXP + (size_t)NEDGES * HEADS;      // N*HEADS
    float* ASRC = DEN  + (size_t)NNODES * HEADS;      // N*HEADS
    float* ADST = ASRC + (size_t)NNODES * HEADS;      // N*HEADS

    const int dims[4] = {523, 256, 256, 512};
    const float* xin = x0;
    for (int li = 0; li < 3; ++li) {
        int din = dims[li], dout = dims[li + 1];
        int hd = dout / HEADS;
        int hd_shift = (hd == 64) ? 6 : 7;
        int dout_shift = (dout == 256) ? 8 : 9;
        float* outp = (li == 2) ? (float*)d_out : A;

        dim3 gb((dout + 15) / 16, (NNODES + 15) / 16);
        gemm_tiled<<<gb, dim3(16, 16), 0, stream>>>(xin, W[li], Wx, NNODES, din, dout);

        att_scalar<<<(NNODES * HEADS + 255) / 256, 256, 0, stream>>>(Wx, a[li], ASRC, ADST, hd, dout);

        hipMemsetAsync(DEN, 0, (size_t)NNODES * HEADS * sizeof(float), stream);
        edge_logits<<<(NEDGES * HEADS + 255) / 256, 256, 0, stream>>>(src, dst, ASRC, ADST, EEXP, DEN);

        hipMemsetAsync(ACC, 0, (size_t)NNODES * dout * sizeof(float), stream);
        unsigned total = (unsigned)NEDGES << dout_shift;
        scatter_acc<<<(total + 255) / 256, 256, 0, stream>>>(src, dst, EEXP, DEN, Wx, ACC,
                                                             dout_shift, hd_shift);

        elu_ln<<<NNODES, 256, 0, stream>>>(ACC, g[li], bb[li], outp, dout);
        xin = A;
    }
}

// Round 2
// 2188.183 us; speedup vs baseline: 1.8707x; 1.8707x over previous
//
#include <hip/hip_runtime.h>
#include <math.h>

#define NNODES 50000
#define NEDGES 400000
#define HEADS 4
#define NPAD 50048  // 391 * 128

typedef __attribute__((ext_vector_type(8))) short bf16x8;
typedef __attribute__((ext_vector_type(4))) float f32x4;

// ---- fp32 -> bf16 (RNE) ----
__device__ inline unsigned short f2bf(float f) {
    union { float f; unsigned u; } t; t.f = f;
    unsigned u = t.u;
    u += 0x7fffu + ((u >> 16) & 1u);
    return (unsigned short)(u >> 16);
}

// X fp32 [N][din] -> XB bf16 [NPAD][Kp], zero-padded rows/cols
__global__ void conv_x(const float* __restrict__ X, unsigned short* __restrict__ XB,
                       int din, int Kp) {
    int c = blockIdx.x * blockDim.x + threadIdx.x;
    int r = blockIdx.y;
    if (c >= Kp) return;
    unsigned short v = 0;
    if (r < NNODES && c < din) v = f2bf(X[(size_t)r * din + c]);
    XB[(size_t)r * Kp + c] = v;
}

// W fp32 [din][dout] -> Wt bf16 [dout][Kp] (transposed), zero-padded k
__global__ void conv_wt(const float* __restrict__ W, unsigned short* __restrict__ Wt,
                        int din, int dout, int Kp) {
    int k = blockIdx.x * blockDim.x + threadIdx.x;
    int mcol = blockIdx.y;
    if (k >= Kp) return;
    unsigned short v = 0;
    if (k < din) v = f2bf(W[(size_t)k * dout + mcol]);
    Wt[(size_t)mcol * Kp + k] = v;
}

// ---- MFMA GEMM: C[n][m] = A[n][k] * Bt[m][k]^T, bf16 in / fp32 out ----
// 128x128 tile, BK=32, 256 threads (4 waves), each wave 64x64 via 4x4 MFMAs.
__global__ __launch_bounds__(256)
void gemm_mfma(const unsigned short* __restrict__ A, const unsigned short* __restrict__ Bt,
               float* __restrict__ C, int Kp, int m) {
    __shared__ unsigned short sA[128 * 32];
    __shared__ unsigned short sB[128 * 32];
    int tid = threadIdx.x;
    int lane = tid & 63, wave = tid >> 6;
    int wm = (wave & 1) * 64, wn = (wave >> 1) * 64;
    int rowbase = blockIdx.y * 128;
    int colbase = blockIdx.x * 128;

    f32x4 acc[4][4] = {};

    const unsigned short* Ab = A + (size_t)rowbase * Kp;
    const unsigned short* Bb = Bt + (size_t)colbase * Kp;

    // staging: 512 chunks of 16B per tile; chunk c -> row c>>2, col off (c&3)*8
    int c0 = tid, c1 = tid + 256;
    int r0 = c0 >> 2, o0 = (c0 & 3) << 3;
    int r1 = c1 >> 2, o1 = (c1 & 3) << 3;

    int arow = wm + (lane & 15);
    int brow = wn + (lane & 15);
    int koff = (lane >> 4) * 8;

    for (int k0 = 0; k0 < Kp; k0 += 32) {
        __builtin_amdgcn_global_load_lds(
            (const __attribute__((address_space(1))) void*)(Ab + (size_t)r0 * Kp + k0 + o0),
            (__attribute__((address_space(3))) void*)(sA + c0 * 8), 16, 0, 0);
        __builtin_amdgcn_global_load_lds(
            (const __attribute__((address_space(1))) void*)(Ab + (size_t)r1 * Kp + k0 + o1),
            (__attribute__((address_space(3))) void*)(sA + c1 * 8), 16, 0, 0);
        __builtin_amdgcn_global_load_lds(
            (const __attribute__((address_space(1))) void*)(Bb + (size_t)r0 * Kp + k0 + o0),
            (__attribute__((address_space(3))) void*)(sB + c0 * 8), 16, 0, 0);
        __builtin_amdgcn_global_load_lds(
            (const __attribute__((address_space(1))) void*)(Bb + (size_t)r1 * Kp + k0 + o1),
            (__attribute__((address_space(3))) void*)(sB + c1 * 8), 16, 0, 0);
        __syncthreads();  // compiler drains vmcnt before s_barrier

        bf16x8 af[4], bfr[4];
#pragma unroll
        for (int i = 0; i < 4; ++i)
            af[i] = *(const bf16x8*)(sA + (arow + i * 16) * 32 + koff);
#pragma unroll
        for (int i = 0; i < 4; ++i)
            bfr[i] = *(const bf16x8*)(sB + (brow + i * 16) * 32 + koff);
#pragma unroll
        for (int mi = 0; mi < 4; ++mi)
#pragma unroll
            for (int ni = 0; ni < 4; ++ni)
                acc[mi][ni] = __builtin_amdgcn_mfma_f32_16x16x32_bf16(
                    af[mi], bfr[ni], acc[mi][ni], 0, 0, 0);
        __syncthreads();
    }

    // epilogue: C/D layout col=lane&15, row=(lane>>4)*4+reg
    int crow0 = rowbase + wm + (lane >> 4) * 4;
    int ccol0 = colbase + wn + (lane & 15);
#pragma unroll
    for (int mi = 0; mi < 4; ++mi) {
#pragma unroll
        for (int r = 0; r < 4; ++r) {
            int row = crow0 + mi * 16 + r;
            if (row < NNODES) {
#pragma unroll
                for (int ni = 0; ni < 4; ++ni)
                    C[(size_t)row * m + ccol0 + ni * 16] = acc[mi][ni][r];
            }
        }
    }
}

// -------------- per-(node,head) attention scalars ----------------------------
__global__ void att_scalar(const float* __restrict__ Wx, const float* __restrict__ a,
                           float* __restrict__ asrc, float* __restrict__ adst,
                           int hd, int dout) {
    int idx = blockIdx.x * blockDim.x + threadIdx.x;
    if (idx >= NNODES * HEADS) return;
    int node = idx >> 2, h = idx & 3;
    const float* base = Wx + (size_t)node * dout + h * hd;
    float s1 = 0.f, s2 = 0.f;
    for (int d = 0; d < hd; ++d) {
        float v = base[d];
        s1 += v * a[d];
        s2 += v * a[hd + d];
    }
    asrc[idx] = s1;
    adst[idx] = s2;
}

// -------------- per-(edge,head) logits -------------------------------------
__global__ void edge_logits(const int* __restrict__ src, const int* __restrict__ dst,
                            const float* __restrict__ asrc, const float* __restrict__ adst,
                            float* __restrict__ eexp, float* __restrict__ den) {
    int idx = blockIdx.x * blockDim.x + threadIdx.x;
    if (idx >= NEDGES * HEADS) return;
    int e = idx >> 2, h = idx & 3;
    int s = src[e], d = dst[e];
    float x = asrc[s * HEADS + h] + adst[d * HEADS + h];
    x = x > 0.f ? x : 0.2f * x;
    float ex = expf(x);
    eexp[idx] = ex;
    atomicAdd(&den[d * HEADS + h], ex);
}

// -------------- per-(edge,feature) weighted scatter --------------------------
__global__ void scatter_acc(const int* __restrict__ src, const int* __restrict__ dst,
                            const float* __restrict__ eexp, const float* __restrict__ den,
                            const float* __restrict__ Wx, float* __restrict__ acc,
                            int dout_shift, int hd_shift) {
    unsigned idx = blockIdx.x * blockDim.x + threadIdx.x;
    unsigned total = (unsigned)NEDGES << dout_shift;
    if (idx >= total) return;
    unsigned e = idx >> dout_shift;
    unsigned j = idx & ((1u << dout_shift) - 1u);
    unsigned h = j >> hd_shift;
    int s = src[e], d = dst[e];
    float w = eexp[e * HEADS + h] / (den[d * HEADS + h] + 1e-8f);
    atomicAdd(&acc[((size_t)d << dout_shift) + j], w * Wx[((size_t)s << dout_shift) + j]);
}

// -------------- ELU + LayerNorm, one block (256 thr) per node ----------------
__global__ void elu_ln(const float* __restrict__ acc, const float* __restrict__ g,
                       const float* __restrict__ b, float* __restrict__ out, int dout) {
    int node = blockIdx.x;
    int tid = threadIdx.x;
    const float* row = acc + (size_t)node * dout;
    int per = dout >> 8;  // 1 or 2
    float vals[2];
    float lsum = 0.f, lsq = 0.f;
    for (int i = 0; i < per; ++i) {
        float v = row[i * 256 + tid];
        v = v > 0.f ? v : expm1f(v);
        vals[i] = v;
        lsum += v;
        lsq += v * v;
    }
    for (int off = 32; off; off >>= 1) {
        lsum += __shfl_down(lsum, off);
        lsq += __shfl_down(lsq, off);
    }
    __shared__ float ssum[4], ssq[4];
    __shared__ float smean, srstd;
    int wid = tid >> 6, lane = tid & 63;
    if (lane == 0) { ssum[wid] = lsum; ssq[wid] = lsq; }
    __syncthreads();
    if (tid == 0) {
        float ts = ssum[0] + ssum[1] + ssum[2] + ssum[3];
        float tq = ssq[0] + ssq[1] + ssq[2] + ssq[3];
        float mean = ts / dout;
        float var = tq / dout - mean * mean;
        smean = mean;
        srstd = rsqrtf(var + 1e-5f);
    }
    __syncthreads();
    float mean = smean, rstd = srstd;
    for (int i = 0; i < per; ++i) {
        int j = i * 256 + tid;
        out[(size_t)node * dout + j] = (vals[i] - mean) * rstd * g[j] + b[j];
    }
}

extern "C" void kernel_launch(void* const* d_in, const int* in_sizes, int n_in,
                              void* d_out, int out_size, void* d_ws, size_t ws_size,
                              hipStream_t stream) {
    const float* x0 = (const float*)d_in[0];
    const int* ei = (const int*)d_in[1];
    const int* src = ei;
    const int* dst = ei + NEDGES;
    const float* W[3]  = {(const float*)d_in[2], (const float*)d_in[6],  (const float*)d_in[10]};
    const float* a[3]  = {(const float*)d_in[3], (const float*)d_in[7],  (const float*)d_in[11]};
    const float* g[3]  = {(const float*)d_in[4], (const float*)d_in[8],  (const float*)d_in[12]};
    const float* bb[3] = {(const float*)d_in[5], (const float*)d_in[9],  (const float*)d_in[13]};

    // workspace layout (floats)
    float* A    = (float*)d_ws;                       // N*512 ping buffer
    float* Wx   = A    + (size_t)NNODES * 512;        // N*512
    float* ACC  = Wx   + (size_t)NNODES * 512;        // N*512 (aliased: XB bf16 lives here pre-scatter)
    float* EEXP = ACC  + (size_t)NNODES * 512;        // E*HEADS (aliased: Wt bf16 lives here pre-logits)
    float* DEN  = EEXP + (size_t)NEDGES * HEADS;
    float* ASRC = DEN  + (size_t)NNODES * HEADS;
    float* ADST = ASRC + (size_t)NNODES * HEADS;

    unsigned short* XB = (unsigned short*)ACC;   // [NPAD][Kp]  (<= 54.5 MB < 102.4 MB)
    unsigned short* Wt = (unsigned short*)EEXP;  // [dout][Kp]  (<= 0.56 MB < 6.4 MB)

    const int dims[4] = {523, 256, 256, 512};
    const int Kps[3] = {544, 256, 256};
    const float* xin = x0;
    for (int li = 0; li < 3; ++li) {
        int din = dims[li], dout = dims[li + 1];
        int Kp = Kps[li];
        int hd = dout / HEADS;
        int hd_shift = (hd == 64) ? 6 : 7;
        int dout_shift = (dout == 256) ? 8 : 9;
        float* outp = (li == 2) ? (float*)d_out : A;

        // stage inputs as bf16 (XB aliases ACC: safe, ACC zeroed only at scatter)
        conv_x<<<dim3((Kp + 255) / 256, NPAD), 256, 0, stream>>>(xin, XB, din, Kp);
        conv_wt<<<dim3((Kp + 255) / 256, dout), 256, 0, stream>>>(W[li], Wt, din, dout, Kp);

        gemm_mfma<<<dim3(dout / 128, NPAD / 128), 256, 0, stream>>>(XB, Wt, Wx, Kp, dout);

        att_scalar<<<(NNODES * HEADS + 255) / 256, 256, 0, stream>>>(Wx, a[li], ASRC, ADST, hd, dout);

        hipMemsetAsync(DEN, 0, (size_t)NNODES * HEADS * sizeof(float), stream);
        edge_logits<<<(NEDGES * HEADS + 255) / 256, 256, 0, stream>>>(src, dst, ASRC, ADST, EEXP, DEN);

        hipMemsetAsync(ACC, 0, (size_t)NNODES * dout * sizeof(float), stream);
        unsigned total = (unsigned)NEDGES << dout_shift;
        scatter_acc<<<(total + 255) / 256, 256, 0, stream>>>(src, dst, EEXP, DEN, Wx, ACC,
                                                             dout_shift, hd_shift);

        elu_ln<<<NNODES, 256, 0, stream>>>(ACC, g[li], bb[li], outp, dout);
        xin = A;
    }
}

// Round 3
// 1070.299 us; speedup vs baseline: 3.8246x; 2.0445x over previous
//
#include <hip/hip_runtime.h>
#include <math.h>

#define NNODES 50000
#define NEDGES 400000
#define HEADS 4
#define NPAD 50048  // 391 * 128

typedef __attribute__((ext_vector_type(8))) short bf16x8;
typedef __attribute__((ext_vector_type(4))) float f32x4;

__device__ inline unsigned short f2bf(float f) {
    union { float f; unsigned u; } t; t.f = f;
    unsigned u = t.u;
    u += 0x7fffu + ((u >> 16) & 1u);
    return (unsigned short)(u >> 16);
}
__device__ inline float bf2f(unsigned short s) {
    union { unsigned u; float f; } t; t.u = ((unsigned)s) << 16;
    return t.f;
}

// ---------------- CSR build (edge_index is constant across layers) -----------
__global__ void count_deg(const int* __restrict__ dst, int* __restrict__ cnt) {
    int e = blockIdx.x * blockDim.x + threadIdx.x;
    if (e < NEDGES) atomicAdd(&cnt[dst[e]], 1);
}

// single-block exclusive scan over cnt[0..n) -> rowptr, cursor
__global__ void scan_rowptr(const int* __restrict__ cnt, int* __restrict__ rowptr,
                            int* __restrict__ cursor, int n) {
    __shared__ int sums[1024];
    int tid = threadIdx.x;
    int CH = (n + 1023) / 1024;
    int lo = tid * CH, hi = min(lo + CH, n);
    int s = 0;
    for (int i = lo; i < hi; ++i) s += cnt[i];
    sums[tid] = s;
    __syncthreads();
    for (int off = 1; off < 1024; off <<= 1) {
        int t = (tid >= off) ? sums[tid - off] : 0;
        __syncthreads();
        sums[tid] += t;
        __syncthreads();
    }
    int run = sums[tid] - s;
    for (int i = lo; i < hi; ++i) {
        rowptr[i] = run; cursor[i] = run;
        run += cnt[i];
    }
    if (tid == 1023) rowptr[n] = run;
}

__global__ void fill_csr(const int* __restrict__ src, const int* __restrict__ dst,
                         int* __restrict__ cursor, int* __restrict__ srcs,
                         int* __restrict__ epos) {
    int e = blockIdx.x * blockDim.x + threadIdx.x;
    if (e >= NEDGES) return;
    int p = atomicAdd(&cursor[dst[e]], 1);
    srcs[p] = src[e];
    epos[e] = p;
}

// X fp32 [N][din] -> XB bf16 [NPAD][Kp] (layer 0 only)
__global__ void conv_x(const float* __restrict__ X, unsigned short* __restrict__ XB,
                       int din, int Kp) {
    int c = blockIdx.x * blockDim.x + threadIdx.x;
    int r = blockIdx.y;
    if (c >= Kp) return;
    unsigned short v = 0;
    if (r < NNODES && c < din) v = f2bf(X[(size_t)r * din + c]);
    XB[(size_t)r * Kp + c] = v;
}

// W fp32 [din][dout] -> Wt bf16 [dout][Kp]
__global__ void conv_wt(const float* __restrict__ W, unsigned short* __restrict__ Wt,
                        int din, int dout, int Kp) {
    int k = blockIdx.x * blockDim.x + threadIdx.x;
    int mcol = blockIdx.y;
    if (k >= Kp) return;
    unsigned short v = 0;
    if (k < din) v = f2bf(W[(size_t)k * dout + mcol]);
    Wt[(size_t)mcol * Kp + k] = v;
}

// ---- MFMA GEMM: C[n][m] = A[n][k] * Bt[m][k]^T, bf16 in / bf16 out ----
__global__ __launch_bounds__(256)
void gemm_mfma(const unsigned short* __restrict__ A, const unsigned short* __restrict__ Bt,
               unsigned short* __restrict__ C, int Kp, int m) {
    __shared__ unsigned short sA[128 * 32];
    __shared__ unsigned short sB[128 * 32];
    int tid = threadIdx.x;
    int lane = tid & 63, wave = tid >> 6;
    int wm = (wave & 1) * 64, wn = (wave >> 1) * 64;
    int rowbase = blockIdx.y * 128;
    int colbase = blockIdx.x * 128;

    f32x4 acc[4][4] = {};

    const unsigned short* Ab = A + (size_t)rowbase * Kp;
    const unsigned short* Bb = Bt + (size_t)colbase * Kp;

    int c0 = tid, c1 = tid + 256;
    int r0 = c0 >> 2, o0 = (c0 & 3) << 3;
    int r1 = c1 >> 2, o1 = (c1 & 3) << 3;

    int arow = wm + (lane & 15);
    int brow = wn + (lane & 15);
    int koff = (lane >> 4) * 8;

    for (int k0 = 0; k0 < Kp; k0 += 32) {
        __builtin_amdgcn_global_load_lds(
            (const __attribute__((address_space(1))) void*)(Ab + (size_t)r0 * Kp + k0 + o0),
            (__attribute__((address_space(3))) void*)(sA + c0 * 8), 16, 0, 0);
        __builtin_amdgcn_global_load_lds(
            (const __attribute__((address_space(1))) void*)(Ab + (size_t)r1 * Kp + k0 + o1),
            (__attribute__((address_space(3))) void*)(sA + c1 * 8), 16, 0, 0);
        __builtin_amdgcn_global_load_lds(
            (const __attribute__((address_space(1))) void*)(Bb + (size_t)r0 * Kp + k0 + o0),
            (__attribute__((address_space(3))) void*)(sB + c0 * 8), 16, 0, 0);
        __builtin_amdgcn_global_load_lds(
            (const __attribute__((address_space(1))) void*)(Bb + (size_t)r1 * Kp + k0 + o1),
            (__attribute__((address_space(3))) void*)(sB + c1 * 8), 16, 0, 0);
        __syncthreads();

        bf16x8 af[4], bfr[4];
#pragma unroll
        for (int i = 0; i < 4; ++i)
            af[i] = *(const bf16x8*)(sA + (arow + i * 16) * 32 + koff);
#pragma unroll
        for (int i = 0; i < 4; ++i)
            bfr[i] = *(const bf16x8*)(sB + (brow + i * 16) * 32 + koff);
#pragma unroll
        for (int mi = 0; mi < 4; ++mi)
#pragma unroll
            for (int ni = 0; ni < 4; ++ni)
                acc[mi][ni] = __builtin_amdgcn_mfma_f32_16x16x32_bf16(
                    af[mi], bfr[ni], acc[mi][ni], 0, 0, 0);
        __syncthreads();
    }

    int crow0 = rowbase + wm + (lane >> 4) * 4;
    int ccol0 = colbase + wn + (lane & 15);
#pragma unroll
    for (int mi = 0; mi < 4; ++mi) {
#pragma unroll
        for (int r = 0; r < 4; ++r) {
            int row = crow0 + mi * 16 + r;
            if (row < NNODES) {
#pragma unroll
                for (int ni = 0; ni < 4; ++ni)
                    C[(size_t)row * m + ccol0 + ni * 16] = f2bf(acc[mi][ni][r]);
            }
        }
    }
}

// -------------- per-(node,head) attention scalars (bf16 Wx) ------------------
__global__ void att_scalar(const unsigned short* __restrict__ Wx, const float* __restrict__ a,
                           float* __restrict__ asrc, float* __restrict__ adst,
                           int hd, int dout) {
    int idx = blockIdx.x * blockDim.x + threadIdx.x;
    if (idx >= NNODES * HEADS) return;
    int node = idx >> 2, h = idx & 3;
    const unsigned short* base = Wx + (size_t)node * dout + h * hd;
    float s1 = 0.f, s2 = 0.f;
    for (int d = 0; d < hd; ++d) {
        float v = bf2f(base[d]);
        s1 += v * a[d];
        s2 += v * a[hd + d];
    }
    asrc[idx] = s1;
    adst[idx] = s2;
}

// -------------- per-(edge,head) logits: exp into dst-sorted slot + denom -----
__global__ void edge_logits(const int* __restrict__ src, const int* __restrict__ dst,
                            const int* __restrict__ epos,
                            const float* __restrict__ asrc, const float* __restrict__ adst,
                            float* __restrict__ eexpP, float* __restrict__ den) {
    int idx = blockIdx.x * blockDim.x + threadIdx.x;
    if (idx >= NEDGES * HEADS) return;
    int e = idx >> 2, h = idx & 3;
    int s = src[e], d = dst[e];
    float x = asrc[s * HEADS + h] + adst[d * HEADS + h];
    x = x > 0.f ? x : 0.2f * x;
    float ex = expf(x);
    eexpP[(size_t)epos[e] * HEADS + h] = ex;
    atomicAdd(&den[d * HEADS + h], ex);
}

// -------------- fused gather-aggregate + ELU + LayerNorm ---------------------
// one block (256 thr) per dst node
template <int DOUT, bool OUT_BF>
__global__ __launch_bounds__(256)
void aggregate_fused(const int* __restrict__ rowptr, const int* __restrict__ srcs,
                     const float* __restrict__ eexpP, const float* __restrict__ den,
                     const unsigned short* __restrict__ WxB,
                     const float* __restrict__ g, const float* __restrict__ b,
                     void* __restrict__ outp) {
    constexpr int PER = DOUT / 256;          // 1 or 2
    constexpr int HD_SHIFT = (DOUT / HEADS == 64) ? 6 : 7;
    int d = blockIdx.x;
    int tid = threadIdx.x;
    int beg = rowptr[d], end = rowptr[d + 1];

    int j0 = tid, j1 = tid + 256;
    int h0 = j0 >> HD_SHIFT;
    float acc0 = 0.f, acc1 = 0.f;
    float rd0 = 1.f / (den[d * HEADS + h0] + 1e-8f);
    float rd1 = 0.f;
    int h1 = 0;
    if constexpr (PER == 2) {
        h1 = j1 >> HD_SHIFT;
        rd1 = 1.f / (den[d * HEADS + h1] + 1e-8f);
    }

    __shared__ int s_s[64];
    __shared__ float s_e[256];
    for (int cb = beg; cb < end; cb += 64) {
        int mcnt = min(64, end - cb);
        __syncthreads();
        if (tid < mcnt) s_s[tid] = srcs[cb + tid];
        if (tid < mcnt * HEADS) s_e[tid] = eexpP[(size_t)cb * HEADS + tid];
        __syncthreads();
        for (int i = 0; i < mcnt; ++i) {
            int s = s_s[i];
            float w0 = s_e[i * HEADS + h0] * rd0;
            acc0 = fmaf(w0, bf2f(WxB[(size_t)s * DOUT + j0]), acc0);
            if constexpr (PER == 2) {
                float w1 = s_e[i * HEADS + h1] * rd1;
                acc1 = fmaf(w1, bf2f(WxB[(size_t)s * DOUT + j1]), acc1);
            }
        }
    }

    // ELU
    float v0 = acc0 > 0.f ? acc0 : expm1f(acc0);
    float v1 = 0.f;
    if constexpr (PER == 2) v1 = acc1 > 0.f ? acc1 : expm1f(acc1);

    float lsum = v0 + v1, lsq = v0 * v0 + v1 * v1;
    for (int off = 32; off; off >>= 1) {
        lsum += __shfl_down(lsum, off);
        lsq += __shfl_down(lsq, off);
    }
    __shared__ float ssum[4], ssq[4];
    __shared__ float smean, srstd;
    int wid = tid >> 6, lane = tid & 63;
    if (lane == 0) { ssum[wid] = lsum; ssq[wid] = lsq; }
    __syncthreads();
    if (tid == 0) {
        float ts = ssum[0] + ssum[1] + ssum[2] + ssum[3];
        float tq = ssq[0] + ssq[1] + ssq[2] + ssq[3];
        float mean = ts / DOUT;
        float var = tq / DOUT - mean * mean;
        smean = mean;
        srstd = rsqrtf(var + 1e-5f);
    }
    __syncthreads();
    float mean = smean, rstd = srstd;

    float r0 = (v0 - mean) * rstd * g[j0] + b[j0];
    if constexpr (OUT_BF)
        ((unsigned short*)outp)[(size_t)d * DOUT + j0] = f2bf(r0);
    else
        ((float*)outp)[(size_t)d * DOUT + j0] = r0;
    if constexpr (PER == 2) {
        float r1 = (v1 - mean) * rstd * g[j1] + b[j1];
        if constexpr (OUT_BF)
            ((unsigned short*)outp)[(size_t)d * DOUT + j1] = f2bf(r1);
        else
            ((float*)outp)[(size_t)d * DOUT + j1] = r1;
    }
}

extern "C" void kernel_launch(void* const* d_in, const int* in_sizes, int n_in,
                              void* d_out, int out_size, void* d_ws, size_t ws_size,
                              hipStream_t stream) {
    const float* x0 = (const float*)d_in[0];
    const int* ei = (const int*)d_in[1];
    const int* src = ei;
    const int* dst = ei + NEDGES;
    const float* W[3]  = {(const float*)d_in[2], (const float*)d_in[6],  (const float*)d_in[10]};
    const float* a[3]  = {(const float*)d_in[3], (const float*)d_in[7],  (const float*)d_in[11]};
    const float* g[3]  = {(const float*)d_in[4], (const float*)d_in[8],  (const float*)d_in[12]};
    const float* bb[3] = {(const float*)d_in[5], (const float*)d_in[9],  (const float*)d_in[13]};

    // ---- workspace carve (256B aligned) ----
    char* p = (char*)d_ws;
    auto carve = [&](size_t bytes) {
        char* r = p;
        p += (bytes + 255) & ~(size_t)255;
        return r;
    };
    unsigned short* XB   = (unsigned short*)carve((size_t)NPAD * 544 * 2);   // 54.5 MB
    unsigned short* WxB  = (unsigned short*)carve((size_t)NNODES * 512 * 2); // 51.2 MB
    unsigned short* Wt   = (unsigned short*)carve((size_t)512 * 544 * 2);
    float* EEXPP = (float*)carve((size_t)NEDGES * HEADS * 4);                // 6.4 MB
    float* DEN   = (float*)carve((size_t)NNODES * HEADS * 4);
    float* ASRC  = (float*)carve((size_t)NNODES * HEADS * 4);
    float* ADST  = (float*)carve((size_t)NNODES * HEADS * 4);
    int* CNT  = (int*)carve((size_t)NNODES * 4);
    int* ROWP = (int*)carve((size_t)(NNODES + 1) * 4);
    int* CURS = (int*)carve((size_t)NNODES * 4);
    int* SRCS = (int*)carve((size_t)NEDGES * 4);
    int* EPOS = (int*)carve((size_t)NEDGES * 4);

    // ---- CSR build (edge_index constant across layers; rebuilt every call) ----
    hipMemsetAsync(CNT, 0, (size_t)NNODES * 4, stream);
    count_deg<<<(NEDGES + 255) / 256, 256, 0, stream>>>(dst, CNT);
    scan_rowptr<<<1, 1024, 0, stream>>>(CNT, ROWP, CURS, NNODES);
    fill_csr<<<(NEDGES + 255) / 256, 256, 0, stream>>>(src, dst, CURS, SRCS, EPOS);

    const int dims[4] = {523, 256, 256, 512};
    const int Kps[3] = {544, 256, 256};
    for (int li = 0; li < 3; ++li) {
        int din = dims[li], dout = dims[li + 1];
        int Kp = Kps[li];
        int hd = dout / HEADS;

        if (li == 0) {
            conv_x<<<dim3((Kp + 255) / 256, NPAD), 256, 0, stream>>>(x0, XB, din, Kp);
        }
        // (layers 1,2: XB was written by previous aggregate; zero the pad tail)
        conv_wt<<<dim3((Kp + 255) / 256, dout), 256, 0, stream>>>(W[li], Wt, din, dout, Kp);

        gemm_mfma<<<dim3(dout / 128, NPAD / 128), 256, 0, stream>>>(XB, Wt, WxB, Kp, dout);

        att_scalar<<<(NNODES * HEADS + 255) / 256, 256, 0, stream>>>(WxB, a[li], ASRC, ADST, hd, dout);

        hipMemsetAsync(DEN, 0, (size_t)NNODES * HEADS * 4, stream);
        edge_logits<<<(NEDGES * HEADS + 255) / 256, 256, 0, stream>>>(src, dst, EPOS, ASRC, ADST,
                                                                      EEXPP, DEN);

        if (li == 0) {
            aggregate_fused<256, true><<<NNODES, 256, 0, stream>>>(
                ROWP, SRCS, EEXPP, DEN, WxB, g[li], bb[li], (void*)XB);
            hipMemsetAsync(XB + (size_t)NNODES * 256, 0, (size_t)(NPAD - NNODES) * 256 * 2, stream);
        } else if (li == 1) {
            aggregate_fused<256, true><<<NNODES, 256, 0, stream>>>(
                ROWP, SRCS, EEXPP, DEN, WxB, g[li], bb[li], (void*)XB);
            hipMemsetAsync(XB + (size_t)NNODES * 256, 0, (size_t)(NPAD - NNODES) * 256 * 2, stream);
        } else {
            aggregate_fused<512, false><<<NNODES, 256, 0, stream>>>(
                ROWP, SRCS, EEXPP, DEN, WxB, g[li], bb[li], d_out);
        }
    }
}

// Round 4
// 881.861 us; speedup vs baseline: 4.6418x; 1.2137x over previous
//
#include <hip/hip_runtime.h>
#include <math.h>

#define NNODES 50000
#define NEDGES 400000
#define HEADS 4
#define NPAD 50048  // 391 * 128

typedef __attribute__((ext_vector_type(8))) short bf16x8;
typedef __attribute__((ext_vector_type(4))) float f32x4;
typedef __attribute__((ext_vector_type(4))) unsigned short u16x4;

__device__ inline unsigned short f2bf(float f) {
    union { float f; unsigned u; } t; t.f = f;
    unsigned u = t.u;
    u += 0x7fffu + ((u >> 16) & 1u);
    return (unsigned short)(u >> 16);
}
__device__ inline float bf2f(unsigned short s) {
    union { unsigned u; float f; } t; t.u = ((unsigned)s) << 16;
    return t.f;
}

// ---------------- CSR build (edge_index is constant across layers) -----------
__global__ void count_deg(const int* __restrict__ dst, int* __restrict__ cnt) {
    int e = blockIdx.x * blockDim.x + threadIdx.x;
    if (e < NEDGES) atomicAdd(&cnt[dst[e]], 1);
}

__global__ void scan_rowptr(const int* __restrict__ cnt, int* __restrict__ rowptr,
                            int* __restrict__ cursor, int n) {
    __shared__ int sums[1024];
    int tid = threadIdx.x;
    int CH = (n + 1023) / 1024;
    int lo = tid * CH, hi = min(lo + CH, n);
    int s = 0;
    for (int i = lo; i < hi; ++i) s += cnt[i];
    sums[tid] = s;
    __syncthreads();
    for (int off = 1; off < 1024; off <<= 1) {
        int t = (tid >= off) ? sums[tid - off] : 0;
        __syncthreads();
        sums[tid] += t;
        __syncthreads();
    }
    int run = sums[tid] - s;
    for (int i = lo; i < hi; ++i) {
        rowptr[i] = run; cursor[i] = run;
        run += cnt[i];
    }
    if (tid == 1023) rowptr[n] = run;
}

__global__ void fill_csr(const int* __restrict__ src, const int* __restrict__ dst,
                         int* __restrict__ cursor, int* __restrict__ srcs,
                         int* __restrict__ epos) {
    int e = blockIdx.x * blockDim.x + threadIdx.x;
    if (e >= NEDGES) return;
    int p = atomicAdd(&cursor[dst[e]], 1);
    srcs[p] = src[e];
    epos[e] = p;
}

// X fp32 [N][din] -> XB bf16 [NPAD][Kp] (layer 0 only)
__global__ void conv_x(const float* __restrict__ X, unsigned short* __restrict__ XB,
                       int din, int Kp) {
    int c = blockIdx.x * blockDim.x + threadIdx.x;
    int r = blockIdx.y;
    if (c >= Kp) return;
    unsigned short v = 0;
    if (r < NNODES && c < din) v = f2bf(X[(size_t)r * din + c]);
    XB[(size_t)r * Kp + c] = v;
}

// W fp32 [din][dout] -> Wt bf16 [dout][Kp]
__global__ void conv_wt(const float* __restrict__ W, unsigned short* __restrict__ Wt,
                        int din, int dout, int Kp) {
    int k = blockIdx.x * blockDim.x + threadIdx.x;
    int mcol = blockIdx.y;
    if (k >= Kp) return;
    unsigned short v = 0;
    if (k < din) v = f2bf(W[(size_t)k * dout + mcol]);
    Wt[(size_t)mcol * Kp + k] = v;
}

// ---- MFMA GEMM: C[n][m] = A[n][k] * Bt[m][k]^T, bf16 in / bf16 out ----
__global__ __launch_bounds__(256)
void gemm_mfma(const unsigned short* __restrict__ A, const unsigned short* __restrict__ Bt,
               unsigned short* __restrict__ C, int Kp, int m) {
    __shared__ unsigned short sA[128 * 32];
    __shared__ unsigned short sB[128 * 32];
    int tid = threadIdx.x;
    int lane = tid & 63, wave = tid >> 6;
    int wm = (wave & 1) * 64, wn = (wave >> 1) * 64;
    int rowbase = blockIdx.y * 128;
    int colbase = blockIdx.x * 128;

    f32x4 acc[4][4] = {};

    const unsigned short* Ab = A + (size_t)rowbase * Kp;
    const unsigned short* Bb = Bt + (size_t)colbase * Kp;

    int c0 = tid, c1 = tid + 256;
    int r0 = c0 >> 2, o0 = (c0 & 3) << 3;
    int r1 = c1 >> 2, o1 = (c1 & 3) << 3;

    int arow = wm + (lane & 15);
    int brow = wn + (lane & 15);
    int koff = (lane >> 4) * 8;

    for (int k0 = 0; k0 < Kp; k0 += 32) {
        __builtin_amdgcn_global_load_lds(
            (const __attribute__((address_space(1))) void*)(Ab + (size_t)r0 * Kp + k0 + o0),
            (__attribute__((address_space(3))) void*)(sA + c0 * 8), 16, 0, 0);
        __builtin_amdgcn_global_load_lds(
            (const __attribute__((address_space(1))) void*)(Ab + (size_t)r1 * Kp + k0 + o1),
            (__attribute__((address_space(3))) void*)(sA + c1 * 8), 16, 0, 0);
        __builtin_amdgcn_global_load_lds(
            (const __attribute__((address_space(1))) void*)(Bb + (size_t)r0 * Kp + k0 + o0),
            (__attribute__((address_space(3))) void*)(sB + c0 * 8), 16, 0, 0);
        __builtin_amdgcn_global_load_lds(
            (const __attribute__((address_space(1))) void*)(Bb + (size_t)r1 * Kp + k0 + o1),
            (__attribute__((address_space(3))) void*)(sB + c1 * 8), 16, 0, 0);
        __syncthreads();

        bf16x8 af[4], bfr[4];
#pragma unroll
        for (int i = 0; i < 4; ++i)
            af[i] = *(const bf16x8*)(sA + (arow + i * 16) * 32 + koff);
#pragma unroll
        for (int i = 0; i < 4; ++i)
            bfr[i] = *(const bf16x8*)(sB + (brow + i * 16) * 32 + koff);
#pragma unroll
        for (int mi = 0; mi < 4; ++mi)
#pragma unroll
            for (int ni = 0; ni < 4; ++ni)
                acc[mi][ni] = __builtin_amdgcn_mfma_f32_16x16x32_bf16(
                    af[mi], bfr[ni], acc[mi][ni], 0, 0, 0);
        __syncthreads();
    }

    int crow0 = rowbase + wm + (lane >> 4) * 4;
    int ccol0 = colbase + wn + (lane & 15);
#pragma unroll
    for (int mi = 0; mi < 4; ++mi) {
#pragma unroll
        for (int r = 0; r < 4; ++r) {
            int row = crow0 + mi * 16 + r;
            if (row < NNODES) {
#pragma unroll
                for (int ni = 0; ni < 4; ++ni)
                    C[(size_t)row * m + ccol0 + ni * 16] = f2bf(acc[mi][ni][r]);
            }
        }
    }
}

// -------------- attention scalars: one wave per node, coalesced --------------
template <int DOUT>
__global__ __launch_bounds__(256)
void att_scalar_v2(const unsigned short* __restrict__ Wx, const float* __restrict__ a,
                   float* __restrict__ asrc, float* __restrict__ adst) {
    constexpr int HD = DOUT / HEADS;   // 64 or 128
    constexpr int PER = DOUT / 64;     // 4 or 8
    __shared__ float sa[2 * HD];
    int tid = threadIdx.x;
    if (tid < 2 * HD) sa[tid] = a[tid];
    __syncthreads();

    int wave = tid >> 6, lane = tid & 63;
    int node = blockIdx.x * 4 + wave;
    if (node >= NNODES) return;

    int j = lane * PER;
    int h = lane >> 4;                 // head (both DOUT cases)
    int dl = (lane & 15) * PER;        // local d within head
    const unsigned short* base = Wx + (size_t)node * DOUT + j;

    float s1 = 0.f, s2 = 0.f;
#pragma unroll
    for (int t = 0; t < PER; t += 4) {
        u16x4 v4 = *(const u16x4*)(base + t);
#pragma unroll
        for (int q = 0; q < 4; ++q) {
            float v = bf2f(v4[q]);
            s1 = fmaf(v, sa[dl + t + q], s1);
            s2 = fmaf(v, sa[HD + dl + t + q], s2);
        }
    }
    // reduce within 16-lane head groups
#pragma unroll
    for (int off = 1; off < 16; off <<= 1) {
        s1 += __shfl_xor(s1, off);
        s2 += __shfl_xor(s2, off);
    }
    if ((lane & 15) == 0) {
        asrc[node * HEADS + h] = s1;
        adst[node * HEADS + h] = s2;
    }
}

// -------------- per-(edge,head) logits: exp into dst-sorted slot + denom -----
__global__ void edge_logits(const int* __restrict__ src, const int* __restrict__ dst,
                            const int* __restrict__ epos,
                            const float* __restrict__ asrc, const float* __restrict__ adst,
                            float* __restrict__ eexpP, float* __restrict__ den) {
    int idx = blockIdx.x * blockDim.x + threadIdx.x;
    if (idx >= NEDGES * HEADS) return;
    int e = idx >> 2, h = idx & 3;
    int s = src[e], d = dst[e];
    float x = asrc[s * HEADS + h] + adst[d * HEADS + h];
    x = x > 0.f ? x : 0.2f * x;
    float ex = expf(x);
    eexpP[(size_t)epos[e] * HEADS + h] = ex;
    atomicAdd(&den[d * HEADS + h], ex);
}

// -------------- fused gather-aggregate + ELU + LayerNorm ---------------------
template <int DOUT, bool OUT_BF>
__global__ __launch_bounds__(256)
void aggregate_fused(const int* __restrict__ rowptr, const int* __restrict__ srcs,
                     const float* __restrict__ eexpP, const float* __restrict__ den,
                     const unsigned short* __restrict__ WxB,
                     const float* __restrict__ g, const float* __restrict__ b,
                     void* __restrict__ outp) {
    constexpr int PER = DOUT / 256;          // 1 or 2
    constexpr int HD_SHIFT = (DOUT / HEADS == 64) ? 6 : 7;
    int d = blockIdx.x;
    int tid = threadIdx.x;
    int beg = rowptr[d], end = rowptr[d + 1];

    int j0 = tid, j1 = tid + 256;
    int h0 = j0 >> HD_SHIFT;
    float acc0 = 0.f, acc1 = 0.f;
    float rd0 = 1.f / (den[d * HEADS + h0] + 1e-8f);
    float rd1 = 0.f;
    int h1 = 0;
    if constexpr (PER == 2) {
        h1 = j1 >> HD_SHIFT;
        rd1 = 1.f / (den[d * HEADS + h1] + 1e-8f);
    }

    __shared__ int s_s[64];
    __shared__ float s_e[256];
    for (int cb = beg; cb < end; cb += 64) {
        int mcnt = min(64, end - cb);
        __syncthreads();
        if (tid < mcnt) s_s[tid] = srcs[cb + tid];
        if (tid < mcnt * HEADS) s_e[tid] = eexpP[(size_t)cb * HEADS + tid];
        __syncthreads();
        for (int i = 0; i < mcnt; ++i) {
            int s = s_s[i];
            float w0 = s_e[i * HEADS + h0] * rd0;
            acc0 = fmaf(w0, bf2f(WxB[(size_t)s * DOUT + j0]), acc0);
            if constexpr (PER == 2) {
                float w1 = s_e[i * HEADS + h1] * rd1;
                acc1 = fmaf(w1, bf2f(WxB[(size_t)s * DOUT + j1]), acc1);
            }
        }
    }

    float v0 = acc0 > 0.f ? acc0 : expm1f(acc0);
    float v1 = 0.f;
    if constexpr (PER == 2) v1 = acc1 > 0.f ? acc1 : expm1f(acc1);

    float lsum = v0 + v1, lsq = v0 * v0 + v1 * v1;
    for (int off = 32; off; off >>= 1) {
        lsum += __shfl_down(lsum, off);
        lsq += __shfl_down(lsq, off);
    }
    __shared__ float ssum[4], ssq[4];
    __shared__ float smean, srstd;
    int wid = tid >> 6, lane = tid & 63;
    if (lane == 0) { ssum[wid] = lsum; ssq[wid] = lsq; }
    __syncthreads();
    if (tid == 0) {
        float ts = ssum[0] + ssum[1] + ssum[2] + ssum[3];
        float tq = ssq[0] + ssq[1] + ssq[2] + ssq[3];
        float mean = ts / DOUT;
        float var = tq / DOUT - mean * mean;
        smean = mean;
        srstd = rsqrtf(var + 1e-5f);
    }
    __syncthreads();
    float mean = smean, rstd = srstd;

    float r0 = (v0 - mean) * rstd * g[j0] + b[j0];
    if constexpr (OUT_BF)
        ((unsigned short*)outp)[(size_t)d * DOUT + j0] = f2bf(r0);
    else
        ((float*)outp)[(size_t)d * DOUT + j0] = r0;
    if constexpr (PER == 2) {
        float r1 = (v1 - mean) * rstd * g[j1] + b[j1];
        if constexpr (OUT_BF)
            ((unsigned short*)outp)[(size_t)d * DOUT + j1] = f2bf(r1);
        else
            ((float*)outp)[(size_t)d * DOUT + j1] = r1;
    }
}

extern "C" void kernel_launch(void* const* d_in, const int* in_sizes, int n_in,
                              void* d_out, int out_size, void* d_ws, size_t ws_size,
                              hipStream_t stream) {
    const float* x0 = (const float*)d_in[0];
    const int* ei = (const int*)d_in[1];
    const int* src = ei;
    const int* dst = ei + NEDGES;
    const float* W[3]  = {(const float*)d_in[2], (const float*)d_in[6],  (const float*)d_in[10]};
    const float* a[3]  = {(const float*)d_in[3], (const float*)d_in[7],  (const float*)d_in[11]};
    const float* g[3]  = {(const float*)d_in[4], (const float*)d_in[8],  (const float*)d_in[12]};
    const float* bb[3] = {(const float*)d_in[5], (const float*)d_in[9],  (const float*)d_in[13]};

    char* p = (char*)d_ws;
    auto carve = [&](size_t bytes) {
        char* r = p;
        p += (bytes + 255) & ~(size_t)255;
        return r;
    };
    unsigned short* XB   = (unsigned short*)carve((size_t)NPAD * 544 * 2);
    unsigned short* WxB  = (unsigned short*)carve((size_t)NNODES * 512 * 2);
    unsigned short* Wt   = (unsigned short*)carve((size_t)512 * 544 * 2);
    float* EEXPP = (float*)carve((size_t)NEDGES * HEADS * 4);
    float* DEN   = (float*)carve((size_t)NNODES * HEADS * 4);
    float* ASRC  = (float*)carve((size_t)NNODES * HEADS * 4);
    float* ADST  = (float*)carve((size_t)NNODES * HEADS * 4);
    int* CNT  = (int*)carve((size_t)NNODES * 4);
    int* ROWP = (int*)carve((size_t)(NNODES + 1) * 4);
    int* CURS = (int*)carve((size_t)NNODES * 4);
    int* SRCS = (int*)carve((size_t)NEDGES * 4);
    int* EPOS = (int*)carve((size_t)NEDGES * 4);

    hipMemsetAsync(CNT, 0, (size_t)NNODES * 4, stream);
    count_deg<<<(NEDGES + 255) / 256, 256, 0, stream>>>(dst, CNT);
    scan_rowptr<<<1, 1024, 0, stream>>>(CNT, ROWP, CURS, NNODES);
    fill_csr<<<(NEDGES + 255) / 256, 256, 0, stream>>>(src, dst, CURS, SRCS, EPOS);

    const int dims[4] = {523, 256, 256, 512};
    const int Kps[3] = {544, 256, 256};
    for (int li = 0; li < 3; ++li) {
        int din = dims[li], dout = dims[li + 1];
        int Kp = Kps[li];

        if (li == 0) {
            conv_x<<<dim3((Kp + 255) / 256, NPAD), 256, 0, stream>>>(x0, XB, din, Kp);
        }
        conv_wt<<<dim3((Kp + 255) / 256, dout), 256, 0, stream>>>(W[li], Wt, din, dout, Kp);

        gemm_mfma<<<dim3(dout / 128, NPAD / 128), 256, 0, stream>>>(XB, Wt, WxB, Kp, dout);

        if (dout == 256)
            att_scalar_v2<256><<<(NNODES + 3) / 4, 256, 0, stream>>>(WxB, a[li], ASRC, ADST);
        else
            att_scalar_v2<512><<<(NNODES + 3) / 4, 256, 0, stream>>>(WxB, a[li], ASRC, ADST);

        hipMemsetAsync(DEN, 0, (size_t)NNODES * HEADS * 4, stream);
        edge_logits<<<(NEDGES * HEADS + 255) / 256, 256, 0, stream>>>(src, dst, EPOS, ASRC, ADST,
                                                                      EEXPP, DEN);

        if (li == 2) {
            aggregate_fused<512, false><<<NNODES, 256, 0, stream>>>(
                ROWP, SRCS, EEXPP, DEN, WxB, g[li], bb[li], d_out);
        } else {
            aggregate_fused<256, true><<<NNODES, 256, 0, stream>>>(
                ROWP, SRCS, EEXPP, DEN, WxB, g[li], bb[li], (void*)XB);
            hipMemsetAsync(XB + (size_t)NNODES * 256, 0, (size_t)(NPAD - NNODES) * 256 * 2, stream);
        }
    }
}